// Round 7
// baseline (362.570 us; speedup 1.0000x reference)
//
#include <hip/hip_runtime.h>

// MessagePassing: 10 iterations of 3x3 per-pixel-weighted smoothing.
//   input [8,64,128,128] f32, weight [8,9,128,128] f32 -> out [8,64,128,128] f32
// R7 = R6 (two 5-step fused kernels, full-width 128W x 16H core, 26-row region,
// 4 px/thread = 36 weight regs, permuted conflict-free LDS, 256 blocks) +
//  1. asm-pin the 36 weights AFTER load+select. R6's VGPR=64 proved the
//     allocator remat'd the weight loads into the step loop (9 L2-latency
//     loads per thread-step -> VALUBusy 11%). Here pressure ~100 < 128 cap
//     (13 waves => >=4 on one SIMD), so pinning sticks without spill.
//  2. Overlap next-chunk global loads (reg-staged) with the store phase;
//     6 barriers/chunk instead of 7.

#define NB    8
#define CC    64
#define HH    128
#define WW    128
#define TAPS  9
#define PLANE (HH * WW)

#define CORE   16            // output tile rows per kernel
#define HALO5  5
#define RROWS  26            // CORE + 2*HALO5
#define RSTR4  129           // LDS row stride in float4 (odd -> +1 bank-group/row)
#define NTH    832           // 26 rows * 32 strips, 13 waves
#define NSTEP  5
#define CGRP   16            // channels per block
#define CSUB   4             // channels per chunk (float4 over channels)
#define LITER  4             // region-load iterations: RROWS*WW / NTH = 3328/832

#define PERM4(J) ((((J) & 3) << 5) | ((J) >> 2))   // bijective on 0..127

#define NWFLOATS (NB * TAPS * PLANE)               // 1,179,648 floats (4.7 MB)

__device__ __forceinline__ float4 fma4(const float4 a, const float s, const float4 c) {
    return make_float4(fmaf(a.x, s, c.x), fmaf(a.y, s, c.y),
                       fmaf(a.z, s, c.z), fmaf(a.w, s, c.w));
}

__global__ __launch_bounds__(256) void mp_norm_kernel(const float* __restrict__ w,
                                                      float* __restrict__ nw) {
    int tid = blockIdx.x * 256 + threadIdx.x;       // 32768 threads
    int wg = tid & 31;
    int h  = (tid >> 5) & 127;
    int n  = tid >> 12;
    int base = n * TAPS * PLANE + h * WW + wg * 4;
    float4 t[TAPS];
    float sx = 1e-5f, sy = 1e-5f, sz = 1e-5f, sw = 1e-5f;
#pragma unroll
    for (int k = 0; k < TAPS; ++k) {
        t[k] = *reinterpret_cast<const float4*>(w + base + k * PLANE);
        sx += t[k].x; sy += t[k].y; sz += t[k].z; sw += t[k].w;
    }
    float rx = 1.0f / sx, ry = 1.0f / sy, rz = 1.0f / sz, rw = 1.0f / sw;
#pragma unroll
    for (int k = 0; k < TAPS; ++k) {
        float4 o = make_float4(t[k].x * rx, t[k].y * ry, t[k].z * rz, t[k].w * rw);
        *reinterpret_cast<float4*>(nw + base + k * PLANE) = o;
    }
}

__global__ __launch_bounds__(NTH, 1) void mp_fused5_kernel(const float* __restrict__ src,
                                                           float* __restrict__ dst,
                                                           const float* __restrict__ nw) {
    __shared__ float4 bufA[RROWS * RSTR4];   // 53,664 B
    __shared__ float4 bufB[RROWS * RSTR4];   // total 107,328 B

    const int bid = blockIdx.x;              // 256 blocks
    const int n   = bid & 7;                 // image -> XCD affinity
    const int ht  = (bid >> 3) & 7;
    const int cg  = bid >> 6;
    const int tr0 = ht * CORE;
    const int cb  = cg * CGRP;

    const int t   = threadIdx.x;
    const int row = t >> 5;                  // 0..25 region row
    const int s   = t & 31;                  // strip: pixels 4s..4s+3

    // ---- per-thread weights: 4 px x 9 taps = 36 regs, then PINNED ----
    float4 wt[TAPS];
    {
        const int gr   = tr0 - HALO5 + row;
        const bool rin = (gr >= 0 && gr < HH);
        const float* nwb = nw + (size_t)n * TAPS * PLANE + (rin ? gr * WW : 0) + s * 4;
#pragma unroll
        for (int k = 0; k < TAPS; ++k) {
            const float4 v = *reinterpret_cast<const float4*>(nwb + k * PLANE);
            wt[k] = rin ? v : make_float4(0.f, 0.f, 0.f, 0.f);  // OOB rows -> 0
        }
    }
    // Forbid remat of the weight loads into the step loop: values must stay
    // in VGPRs (pressure ~100 < 128-reg cap at 13 waves, so no spill either).
#pragma unroll
    for (int k = 0; k < TAPS; ++k) {
        asm volatile("" : "+v"(wt[k].x), "+v"(wt[k].y), "+v"(wt[k].z), "+v"(wt[k].w));
    }

    const float4 z = make_float4(0.f, 0.f, 0.f, 0.f);

    // ---- gather helper data for region loads ----
    const int lr[LITER]  = { t >> 7, (t + NTH) >> 7, (t + 2 * NTH) >> 7, (t + 3 * NTH) >> 7 };
    const int lJ[LITER]  = { t & 127, (t + NTH) & 127, (t + 2 * NTH) & 127, (t + 3 * NTH) & 127 };

    // ---- prologue: load chunk 0 region into bufA ----
    {
        const float* sp = src + ((size_t)n * CC + cb) * PLANE;
#pragma unroll
        for (int it = 0; it < LITER; ++it) {
            const int gr = tr0 - HALO5 + lr[it];
            float4 v = z;
            if (gr >= 0 && gr < HH) {
                const int o = gr * WW + lJ[it];
                v.x = sp[o];
                v.y = sp[PLANE + o];
                v.z = sp[2 * PLANE + o];
                v.w = sp[3 * PLANE + o];
            }
            bufA[lr[it] * RSTR4 + PERM4(lJ[it])] = v;
        }
    }
    __syncthreads();

    for (int ch = 0; ch < CGRP; ch += CSUB) {
        // ---- 5 fused steps, A -> ... -> B, valid rows shrink by 1 per step ----
        float4* pin  = bufA;
        float4* pout = bufB;
        for (int st = 0; st < NSTEP; ++st) {
            const int lo = st + 1;
            const int hi = 24 - st;
            if (row >= lo && row <= hi) {
                float4 acc0 = z, acc1 = z, acc2 = z, acc3 = z;
#pragma unroll
                for (int di = 0; di < 3; ++di) {
                    const float4* rp = pin + (row - 1 + di) * RSTR4;
                    float4 xv[6];
                    xv[0] = (s > 0) ? rp[96 + s - 1] : z;   // col 4s-1
                    xv[1] = rp[s];                          // col 4s
                    xv[2] = rp[32 + s];                     // col 4s+1
                    xv[3] = rp[64 + s];                     // col 4s+2
                    xv[4] = rp[96 + s];                     // col 4s+3
                    xv[5] = (s < 31) ? rp[s + 1] : z;       // col 4s+4
#pragma unroll
                    for (int dj = 0; dj < 3; ++dj) {
                        const int k = di * 3 + dj;
                        acc0 = fma4(xv[0 + dj], wt[k].x, acc0);
                        acc1 = fma4(xv[1 + dj], wt[k].y, acc1);
                        acc2 = fma4(xv[2 + dj], wt[k].z, acc2);
                        acc3 = fma4(xv[3 + dj], wt[k].w, acc3);
                    }
                }
                float4* op = pout + row * RSTR4;
                op[s]      = acc0;
                op[32 + s] = acc1;
                op[64 + s] = acc2;
                op[96 + s] = acc3;
            }
            __syncthreads();
            float4* tmp = pin; pin = pout; pout = tmp;
        }
        // after 5 steps: result in bufB (pin), bufA dead.

        // ---- stage next chunk's region loads (long-latency, issued early) ----
        float4 stage[LITER];
        const bool more = (ch + CSUB < CGRP);
        if (more) {
            const float* sp = src + ((size_t)n * CC + cb + ch + CSUB) * PLANE;
#pragma unroll
            for (int it = 0; it < LITER; ++it) {
                const int gr = tr0 - HALO5 + lr[it];
                float4 v = z;
                if (gr >= 0 && gr < HH) {
                    const int o = gr * WW + lJ[it];
                    v.x = sp[o];
                    v.y = sp[PLANE + o];
                    v.z = sp[2 * PLANE + o];
                    v.w = sp[3 * PLANE + o];
                }
                stage[it] = v;
            }
        }

        // ---- store 16x128 core x 4 channels from bufB (overlaps load latency) ----
        {
            float* dp = dst + ((size_t)n * CC + cb + ch) * PLANE;
            for (int idx = t; idx < CORE * WW; idx += NTH) {
                const int r = idx >> 7;
                const int J = idx & 127;
                const float4 v = pin[(r + HALO5) * RSTR4 + PERM4(J)];
                const int o = (tr0 + r) * WW + J;
                dp[o] = v.x;
                dp[PLANE + o] = v.y;
                dp[2 * PLANE + o] = v.z;
                dp[3 * PLANE + o] = v.w;
            }
        }

        // ---- commit staged region into bufA (dead buffer) ----
        if (more) {
#pragma unroll
            for (int it = 0; it < LITER; ++it)
                bufA[lr[it] * RSTR4 + PERM4(lJ[it])] = stage[it];
        }
        __syncthreads();   // bufB reads done + bufA writes visible
    }
}

extern "C" void kernel_launch(void* const* d_in, const int* in_sizes, int n_in,
                              void* d_out, int out_size, void* d_ws, size_t ws_size,
                              hipStream_t stream) {
    const float* input  = (const float*)d_in[0];
    const float* weight = (const float*)d_in[1];
    float* out = (float*)d_out;
    float* nw  = (float*)d_ws;               // 4.72 MB normalized weights
    float* B0  = nw + NWFLOATS;              // 33.5 MB intermediate (steps 1-5)

    mp_norm_kernel<<<128, 256, 0, stream>>>(weight, nw);
    mp_fused5_kernel<<<256, NTH, 0, stream>>>(input, B0, nw);   // steps 1..5
    mp_fused5_kernel<<<256, NTH, 0, stream>>>(B0, out, nw);     // steps 6..10
}

// Round 8
// 213.615 us; speedup vs baseline: 1.6973x; 1.6973x over previous
//
#include <hip/hip_runtime.h>

// MessagePassing: 10 iterations of 3x3 per-pixel-weighted smoothing.
//   input [8,64,128,128] f32, weight [8,9,128,128] f32 -> out [8,64,128,128] f32
// R8 = R6 structure (two 5-step fused kernels, full-width 128W x 16H core,
// 26-row region, 4 px/thread = 36 weight regs, permuted conflict-free LDS,
// 256 blocks = 1/CU) + amdgpu_waves_per_eu(4,4).
// History: the allocator targets the 8-waves/EU tier (VGPR=64) and remats
// (R6: re-loads weights from global every step, VALUBusy 11%) or spills
// (R7: pin -> 36 values to scratch, +250 MB TCC traffic) to stay there.
// LDS already caps us at 1 block/CU = 13 waves = 4 waves/EU max, so
// requesting exactly 4 waves/EU raises the VGPR budget to 128 at zero
// occupancy cost; weights (36) + acc (16) + xv (24) + addr fit resident.

#define NB    8
#define CC    64
#define HH    128
#define WW    128
#define TAPS  9
#define PLANE (HH * WW)

#define CORE   16            // output tile rows per kernel
#define HALO5  5
#define RROWS  26            // CORE + 2*HALO5
#define RSTR4  129           // LDS row stride in float4 (odd -> +1 bank-group/row)
#define NTH    832           // 26 rows * 32 strips, 13 waves
#define NSTEP  5
#define CGRP   16            // channels per block
#define CSUB   4             // channels per chunk (float4 over channels)

#define PERM4(J) ((((J) & 3) << 5) | ((J) >> 2))   // bijective on 0..127

#define NWFLOATS (NB * TAPS * PLANE)               // 1,179,648 floats (4.7 MB)

__device__ __forceinline__ float4 fma4(const float4 a, const float s, const float4 c) {
    return make_float4(fmaf(a.x, s, c.x), fmaf(a.y, s, c.y),
                       fmaf(a.z, s, c.z), fmaf(a.w, s, c.w));
}

__global__ __launch_bounds__(256) void mp_norm_kernel(const float* __restrict__ w,
                                                      float* __restrict__ nw) {
    int tid = blockIdx.x * 256 + threadIdx.x;       // 32768 threads
    int wg = tid & 31;
    int h  = (tid >> 5) & 127;
    int n  = tid >> 12;
    int base = n * TAPS * PLANE + h * WW + wg * 4;
    float4 t[TAPS];
    float sx = 1e-5f, sy = 1e-5f, sz = 1e-5f, sw = 1e-5f;
#pragma unroll
    for (int k = 0; k < TAPS; ++k) {
        t[k] = *reinterpret_cast<const float4*>(w + base + k * PLANE);
        sx += t[k].x; sy += t[k].y; sz += t[k].z; sw += t[k].w;
    }
    float rx = 1.0f / sx, ry = 1.0f / sy, rz = 1.0f / sz, rw = 1.0f / sw;
#pragma unroll
    for (int k = 0; k < TAPS; ++k) {
        float4 o = make_float4(t[k].x * rx, t[k].y * ry, t[k].z * rz, t[k].w * rw);
        *reinterpret_cast<float4*>(nw + base + k * PLANE) = o;
    }
}

__global__
__attribute__((amdgpu_flat_work_group_size(NTH, NTH), amdgpu_waves_per_eu(4, 4)))
void mp_fused5_kernel(const float* __restrict__ src,
                      float* __restrict__ dst,
                      const float* __restrict__ nw) {
    __shared__ float4 bufA[RROWS * RSTR4];   // 53,664 B
    __shared__ float4 bufB[RROWS * RSTR4];   // total 107,328 B

    const int bid = blockIdx.x;              // 256 blocks
    const int n   = bid & 7;                 // image -> XCD affinity
    const int ht  = (bid >> 3) & 7;
    const int cg  = bid >> 6;
    const int tr0 = ht * CORE;
    const int cb  = cg * CGRP;

    const int t   = threadIdx.x;
    const int row = t >> 5;                  // 0..25 region row
    const int s   = t & 31;                  // strip: pixels 4s..4s+3

    // ---- per-thread weights: 4 px x 9 taps = 36 regs, then pinned ----
    float4 wt[TAPS];
    {
        const int gr   = tr0 - HALO5 + row;
        const bool rin = (gr >= 0 && gr < HH);
        const float* nwb = nw + (size_t)n * TAPS * PLANE + (rin ? gr * WW : 0) + s * 4;
#pragma unroll
        for (int k = 0; k < TAPS; ++k) {
            const float4 v = *reinterpret_cast<const float4*>(nwb + k * PLANE);
            wt[k] = rin ? v : make_float4(0.f, 0.f, 0.f, 0.f);  // OOB rows -> 0
        }
    }
    // With the 128-reg budget from waves_per_eu(4,4), this keeps the loads
    // from being remat'd into the step loop (and there is headroom, so no
    // scratch spill as in R7).
#pragma unroll
    for (int k = 0; k < TAPS; ++k) {
        asm volatile("" : "+v"(wt[k].x), "+v"(wt[k].y), "+v"(wt[k].z), "+v"(wt[k].w));
    }

    const float4 z = make_float4(0.f, 0.f, 0.f, 0.f);

    for (int ch = 0; ch < CGRP; ch += CSUB) {
        const float* sp = src + ((size_t)n * CC + cb + ch) * PLANE;

        // ---- load 26x128 region x 4 channels (permuted layout, zero-pad rows) ----
        for (int idx = t; idx < RROWS * WW; idx += NTH) {      // exactly 4 iters
            const int r  = idx >> 7;
            const int J  = idx & 127;
            const int gr = tr0 - HALO5 + r;
            float4 v = z;
            if (gr >= 0 && gr < HH) {
                const int o = gr * WW + J;
                v.x = sp[o];
                v.y = sp[PLANE + o];
                v.z = sp[2 * PLANE + o];
                v.w = sp[3 * PLANE + o];
            }
            bufA[r * RSTR4 + PERM4(J)] = v;
        }
        __syncthreads();

        // ---- 5 fused steps, valid rows shrink top/bottom by 1 per step ----
        float4* pin  = bufA;
        float4* pout = bufB;
        for (int st = 0; st < NSTEP; ++st) {
            const int lo = st + 1;
            const int hi = 24 - st;
            if (row >= lo && row <= hi) {
                float4 acc0 = z, acc1 = z, acc2 = z, acc3 = z;
#pragma unroll
                for (int di = 0; di < 3; ++di) {
                    const float4* rp = pin + (row - 1 + di) * RSTR4;
                    float4 xv[6];
                    xv[0] = (s > 0) ? rp[96 + s - 1] : z;   // col 4s-1
                    xv[1] = rp[s];                          // col 4s
                    xv[2] = rp[32 + s];                     // col 4s+1
                    xv[3] = rp[64 + s];                     // col 4s+2
                    xv[4] = rp[96 + s];                     // col 4s+3
                    xv[5] = (s < 31) ? rp[s + 1] : z;       // col 4s+4
#pragma unroll
                    for (int dj = 0; dj < 3; ++dj) {
                        const int k = di * 3 + dj;
                        acc0 = fma4(xv[0 + dj], wt[k].x, acc0);
                        acc1 = fma4(xv[1 + dj], wt[k].y, acc1);
                        acc2 = fma4(xv[2 + dj], wt[k].z, acc2);
                        acc3 = fma4(xv[3 + dj], wt[k].w, acc3);
                    }
                }
                float4* op = pout + row * RSTR4;
                op[s]      = acc0;
                op[32 + s] = acc1;
                op[64 + s] = acc2;
                op[96 + s] = acc3;
            }
            __syncthreads();
            float4* tmp = pin; pin = pout; pout = tmp;
        }

        // ---- store 16x128 core x 4 channels ----
        float* dp = dst + ((size_t)n * CC + cb + ch) * PLANE;
        for (int idx = t; idx < CORE * WW; idx += NTH) {
            const int r = idx >> 7;
            const int J = idx & 127;
            const float4 v = pin[(r + HALO5) * RSTR4 + PERM4(J)];
            const int o = (tr0 + r) * WW + J;
            dp[o] = v.x;
            dp[PLANE + o] = v.y;
            dp[2 * PLANE + o] = v.z;
            dp[3 * PLANE + o] = v.w;
        }
        __syncthreads();   // protect bufA before next chunk's load
    }
}

extern "C" void kernel_launch(void* const* d_in, const int* in_sizes, int n_in,
                              void* d_out, int out_size, void* d_ws, size_t ws_size,
                              hipStream_t stream) {
    const float* input  = (const float*)d_in[0];
    const float* weight = (const float*)d_in[1];
    float* out = (float*)d_out;
    float* nw  = (float*)d_ws;               // 4.72 MB normalized weights
    float* B0  = nw + NWFLOATS;              // 33.5 MB intermediate (steps 1-5)

    mp_norm_kernel<<<128, 256, 0, stream>>>(weight, nw);
    mp_fused5_kernel<<<256, NTH, 0, stream>>>(input, B0, nw);   // steps 1..5
    mp_fused5_kernel<<<256, NTH, 0, stream>>>(B0, out, nw);     // steps 6..10
}

// Round 9
// 109.997 us; speedup vs baseline: 3.2962x; 1.9420x over previous
//
#include <hip/hip_runtime.h>
#include <hip/hip_fp16.h>

// MessagePassing: 10 iterations of 3x3 per-pixel-weighted smoothing.
//   input [8,64,128,128] f32, weight [8,9,128,128] f32 -> out [8,64,128,128] f32
// R9 = R6 geometry (two 5-step fused kernels, 128W x 16H core, 26-row region,
// 4 px/thread, permuted conflict-free LDS x-buffers, 256 blocks = 1/CU) with
// weights moved to LDS as fp16.
// Lesson from R6-R8: with this loop the allocator pins itself to the 64-VGPR
// tier and will remat weight loads from global into the step loop (R6, L2
// latency chain every step) or spill pinned weights to scratch (R7/R8, +250MB
// TCC traffic) -- regardless of launch bounds or waves_per_eu. So stop keeping
// weights in VGPRs: put them in LDS (unspillable), read 9x ds_read_b64 per
// step. fp16 makes it fit: 107.3KB x-bufs + 55.3KB weights = 162.6 <= 163.8KB.

#define NB    8
#define CC    64
#define HH    128
#define WW    128
#define TAPS  9
#define PLANE (HH * WW)

#define CORE   16            // output tile rows per kernel
#define HALO5  5
#define RROWS  26            // CORE + 2*HALO5
#define RSTR4  129           // x-buffer row stride in float4
#define NTH    832           // 26 rows * 32 strips, 13 waves
#define NSTEP  5
#define CGRP   16            // channels per block
#define CSUB   4             // channels per chunk (float4 over channels)
#define WROWS  24            // weight rows resident (region rows 1..24)
#define WCELLS (WROWS * TAPS * 32)   // half4 (uint2) cells = 6912 (55,296 B)

#define PERM4(J) ((((J) & 3) << 5) | ((J) >> 2))   // bijective on 0..127

__device__ __forceinline__ float4 fma4(const float4 a, const float s, const float4 c) {
    return make_float4(fmaf(a.x, s, c.x), fmaf(a.y, s, c.y),
                       fmaf(a.z, s, c.z), fmaf(a.w, s, c.w));
}

// Normalize taps and store as fp16, layout [n][9][128][128] halfs (half4 cells).
__global__ __launch_bounds__(256) void mp_norm_kernel(const float* __restrict__ w,
                                                      uint2* __restrict__ nwh) {
    int tid = blockIdx.x * 256 + threadIdx.x;       // 32768 threads
    int wg = tid & 31;
    int h  = (tid >> 5) & 127;
    int n  = tid >> 12;
    int base = n * TAPS * PLANE + h * WW + wg * 4;
    float4 t[TAPS];
    float sx = 1e-5f, sy = 1e-5f, sz = 1e-5f, sw = 1e-5f;
#pragma unroll
    for (int k = 0; k < TAPS; ++k) {
        t[k] = *reinterpret_cast<const float4*>(w + base + k * PLANE);
        sx += t[k].x; sy += t[k].y; sz += t[k].z; sw += t[k].w;
    }
    float rx = 1.0f / sx, ry = 1.0f / sy, rz = 1.0f / sz, rw = 1.0f / sw;
#pragma unroll
    for (int k = 0; k < TAPS; ++k) {
        __half2 a = __floats2half2_rn(t[k].x * rx, t[k].y * ry);
        __half2 b = __floats2half2_rn(t[k].z * rz, t[k].w * rw);
        uint2 v;
        v.x = *reinterpret_cast<unsigned*>(&a);
        v.y = *reinterpret_cast<unsigned*>(&b);
        nwh[((n * TAPS + k) * HH + h) * 32 + wg] = v;
    }
}

__global__ __launch_bounds__(NTH, 1) void mp_fused5_kernel(const float* __restrict__ src,
                                                           float* __restrict__ dst,
                                                           const uint2* __restrict__ nwh) {
    __shared__ float4 bufA[RROWS * RSTR4];   // 53,664 B
    __shared__ float4 bufB[RROWS * RSTR4];   // 53,664 B
    __shared__ uint2  wlds[WCELLS];          // 55,296 B -> total 162,624 B

    const int bid = blockIdx.x;              // 256 blocks
    const int n   = bid & 7;                 // image -> XCD affinity
    const int ht  = (bid >> 3) & 7;
    const int cg  = bid >> 6;
    const int tr0 = ht * CORE;
    const int cb  = cg * CGRP;

    const int t   = threadIdx.x;
    const int row = t >> 5;                  // 0..25 region row
    const int s   = t & 31;                  // strip: pixels 4s..4s+3

    // ---- fill weight LDS once: region rows 1..24, fp16, zero for OOB rows ----
    {
        const uint2* nwb = nwh + (size_t)n * TAPS * (PLANE / 4);
        for (int idx = t; idx < WCELLS; idx += NTH) {        // ~8.3 iters
            const int wrow = idx / (TAPS * 32);
            const int rem  = idx - wrow * (TAPS * 32);
            const int k    = rem >> 5;
            const int ss   = rem & 31;
            const int gr   = tr0 - (HALO5 - 1) + wrow;       // global row of region row wrow+1
            uint2 v = make_uint2(0u, 0u);                    // OOB rows -> zero weights
            if (gr >= 0 && gr < HH)
                v = nwb[(k * HH + gr) * 32 + ss];
            wlds[idx] = v;
        }
    }
    // (visibility of wlds covered by the barrier after the first bufA fill)

    const float4 z = make_float4(0.f, 0.f, 0.f, 0.f);

    for (int ch = 0; ch < CGRP; ch += CSUB) {
        const float* sp = src + ((size_t)n * CC + cb + ch) * PLANE;

        // ---- load 26x128 region x 4 channels (permuted layout, zero-pad rows) ----
        for (int idx = t; idx < RROWS * WW; idx += NTH) {    // exactly 4 iters
            const int r  = idx >> 7;
            const int J  = idx & 127;
            const int gr = tr0 - HALO5 + r;
            float4 v = z;
            if (gr >= 0 && gr < HH) {
                const int o = gr * WW + J;
                v.x = sp[o];
                v.y = sp[PLANE + o];
                v.z = sp[2 * PLANE + o];
                v.w = sp[3 * PLANE + o];
            }
            bufA[r * RSTR4 + PERM4(J)] = v;
        }
        __syncthreads();

        // ---- 5 fused steps, valid rows shrink top/bottom by 1 per step ----
        float4* pin  = bufA;
        float4* pout = bufB;
        for (int st = 0; st < NSTEP; ++st) {
            const int lo = st + 1;
            const int hi = 24 - st;
            if (row >= lo && row <= hi) {
                // Weight base index (half4 cells). asm-opaque so the 9 weight
                // ds_reads cannot be hoisted/CSE'd out of the step loop (which
                // would put 36 floats back under the spill-happy allocator).
                int wb = (row - 1) * (TAPS * 32) + s;
                asm volatile("" : "+v"(wb));
                float4 acc0 = z, acc1 = z, acc2 = z, acc3 = z;
#pragma unroll
                for (int di = 0; di < 3; ++di) {
                    const float4* rp = pin + (row - 1 + di) * RSTR4;
                    float4 xv[6];
                    xv[0] = (s > 0) ? rp[96 + s - 1] : z;   // col 4s-1
                    xv[1] = rp[s];                          // col 4s
                    xv[2] = rp[32 + s];                     // col 4s+1
                    xv[3] = rp[64 + s];                     // col 4s+2
                    xv[4] = rp[96 + s];                     // col 4s+3
                    xv[5] = (s < 31) ? rp[s + 1] : z;       // col 4s+4
#pragma unroll
                    for (int dj = 0; dj < 3; ++dj) {
                        const int k = di * 3 + dj;
                        const uint2 wv = wlds[wb + k * 32];         // ds_read_b64
                        const float2 f01 = __half22float2(*reinterpret_cast<const __half2*>(&wv.x));
                        const float2 f23 = __half22float2(*reinterpret_cast<const __half2*>(&wv.y));
                        acc0 = fma4(xv[0 + dj], f01.x, acc0);
                        acc1 = fma4(xv[1 + dj], f01.y, acc1);
                        acc2 = fma4(xv[2 + dj], f23.x, acc2);
                        acc3 = fma4(xv[3 + dj], f23.y, acc3);
                    }
                }
                float4* op = pout + row * RSTR4;
                op[s]      = acc0;
                op[32 + s] = acc1;
                op[64 + s] = acc2;
                op[96 + s] = acc3;
            }
            __syncthreads();
            float4* tmp = pin; pin = pout; pout = tmp;
        }

        // ---- store 16x128 core x 4 channels ----
        float* dp = dst + ((size_t)n * CC + cb + ch) * PLANE;
        for (int idx = t; idx < CORE * WW; idx += NTH) {
            const int r = idx >> 7;
            const int J = idx & 127;
            const float4 v = pin[(r + HALO5) * RSTR4 + PERM4(J)];
            const int o = (tr0 + r) * WW + J;
            dp[o] = v.x;
            dp[PLANE + o] = v.y;
            dp[2 * PLANE + o] = v.z;
            dp[3 * PLANE + o] = v.w;
        }
        __syncthreads();   // protect bufA/wlds before next chunk's load
    }
}

extern "C" void kernel_launch(void* const* d_in, const int* in_sizes, int n_in,
                              void* d_out, int out_size, void* d_ws, size_t ws_size,
                              hipStream_t stream) {
    const float* input  = (const float*)d_in[0];
    const float* weight = (const float*)d_in[1];
    float* out = (float*)d_out;

    uint2* nwh = (uint2*)d_ws;                               // 2.36 MB fp16 weights
    float* B0  = (float*)((char*)d_ws + (size_t)NB * TAPS * PLANE * 2);  // 33.5 MB

    mp_norm_kernel<<<128, 256, 0, stream>>>(weight, nwh);
    mp_fused5_kernel<<<256, NTH, 0, stream>>>(input, B0, nwh);  // steps 1..5
    mp_fused5_kernel<<<256, NTH, 0, stream>>>(B0, out, nwh);    // steps 6..10
}

// Round 10
// 94.857 us; speedup vs baseline: 3.8223x; 1.1596x over previous
//
#include <hip/hip_runtime.h>
#include <hip/hip_fp16.h>

// MessagePassing: 10 iterations of 3x3 per-pixel-weighted smoothing.
//   input [8,64,128,128] f32, weight [8,9,128,128] f32 -> out [8,64,128,128] f32
// R10 = R9 (two 5-step fused kernels, 128W x 16H core, 26-row region,
// 4 px/thread, permuted LDS, fp16 weights in LDS, 256 blocks = 1/CU) with
// x-buffers ALSO fp16: 8 channels packed per 16B cell. Same LDS instruction
// count per wave-step (18 b128 + 9 b64 + 4 b128w) now serves 8 channels ->
// 2 chunks instead of 4, halving the dominant step-loop LDS time.
// R9 measured: 60us/dispatch, VALUBusy 25%, LDS-pipe bound (conflict counter
// = inherent wave64 b128 serialization, constant since R6).

#define NB    8
#define CC    64
#define HH    128
#define WW    128
#define TAPS  9
#define PLANE (HH * WW)

#define CORE   16            // output tile rows per kernel
#define HALO5  5
#define RROWS  26            // CORE + 2*HALO5
#define RSTR4  129           // x-buffer row stride in cells (uint4)
#define NTH    832           // 26 rows * 32 strips, 13 waves
#define NSTEP  5
#define CGRP   16            // channels per block
#define CSUB   8             // channels per chunk (fp16 x8 in uint4 cell)
#define WROWS  24            // weight rows resident (region rows 1..24)
#define WCELLS (WROWS * TAPS * 32)   // half4 (uint2) cells = 6912 (55,296 B)

#define PERM4(J) ((((J) & 3) << 5) | ((J) >> 2))   // bijective on 0..127

__device__ __forceinline__ float4 fma4(const float4 a, const float s, const float4 c) {
    return make_float4(fmaf(a.x, s, c.x), fmaf(a.y, s, c.y),
                       fmaf(a.z, s, c.z), fmaf(a.w, s, c.w));
}

__device__ __forceinline__ float4 cvt_lo(const uint4 v) {   // ch0-3
    const float2 a = __half22float2(*reinterpret_cast<const __half2*>(&v.x));
    const float2 b = __half22float2(*reinterpret_cast<const __half2*>(&v.y));
    return make_float4(a.x, a.y, b.x, b.y);
}
__device__ __forceinline__ float4 cvt_hi(const uint4 v) {   // ch4-7
    const float2 a = __half22float2(*reinterpret_cast<const __half2*>(&v.z));
    const float2 b = __half22float2(*reinterpret_cast<const __half2*>(&v.w));
    return make_float4(a.x, a.y, b.x, b.y);
}
__device__ __forceinline__ unsigned pack2(float a, float b) {
    __half2 h = __floats2half2_rn(a, b);
    return *reinterpret_cast<unsigned*>(&h);
}

// Normalize taps, store fp16: layout [n][9][128][32] uint2 (half4 cells).
__global__ __launch_bounds__(256) void mp_norm_kernel(const float* __restrict__ w,
                                                      uint2* __restrict__ nwh) {
    int tid = blockIdx.x * 256 + threadIdx.x;       // 32768 threads
    int wg = tid & 31;
    int h  = (tid >> 5) & 127;
    int n  = tid >> 12;
    int base = n * TAPS * PLANE + h * WW + wg * 4;
    float4 t[TAPS];
    float sx = 1e-5f, sy = 1e-5f, sz = 1e-5f, sw = 1e-5f;
#pragma unroll
    for (int k = 0; k < TAPS; ++k) {
        t[k] = *reinterpret_cast<const float4*>(w + base + k * PLANE);
        sx += t[k].x; sy += t[k].y; sz += t[k].z; sw += t[k].w;
    }
    float rx = 1.0f / sx, ry = 1.0f / sy, rz = 1.0f / sz, rw = 1.0f / sw;
#pragma unroll
    for (int k = 0; k < TAPS; ++k) {
        uint2 v;
        v.x = pack2(t[k].x * rx, t[k].y * ry);
        v.y = pack2(t[k].z * rz, t[k].w * rw);
        nwh[((n * TAPS + k) * HH + h) * 32 + wg] = v;
    }
}

__global__ __launch_bounds__(NTH, 1) void mp_fused5_kernel(const float* __restrict__ src,
                                                           float* __restrict__ dst,
                                                           const uint2* __restrict__ nwh) {
    __shared__ uint4 bufA[RROWS * RSTR4];    // 53,664 B (8ch fp16 per cell)
    __shared__ uint4 bufB[RROWS * RSTR4];    // 53,664 B
    __shared__ uint2 wlds[WCELLS];           // 55,296 B -> total 162,624 B

    const int bid = blockIdx.x;              // 256 blocks
    const int n   = bid & 7;                 // image -> XCD affinity
    const int ht  = (bid >> 3) & 7;
    const int cg  = bid >> 6;
    const int tr0 = ht * CORE;
    const int cb  = cg * CGRP;

    const int t   = threadIdx.x;
    const int row = t >> 5;                  // 0..25 region row
    const int s   = t & 31;                  // strip: pixels 4s..4s+3

    // ---- fill weight LDS once: region rows 1..24, fp16, zero for OOB rows ----
    {
        const uint2* nwb = nwh + (size_t)n * TAPS * (PLANE / 4);
        for (int idx = t; idx < WCELLS; idx += NTH) {
            const int wrow = idx / (TAPS * 32);
            const int rem  = idx - wrow * (TAPS * 32);
            const int k    = rem >> 5;
            const int ss   = rem & 31;
            const int gr   = tr0 - (HALO5 - 1) + wrow;   // global row of region row wrow+1
            uint2 v = make_uint2(0u, 0u);                // OOB rows -> zero weights
            if (gr >= 0 && gr < HH)
                v = nwb[(k * HH + gr) * 32 + ss];
            wlds[idx] = v;
        }
    }
    // (visibility covered by the barrier after the first bufA fill)

    const uint4 zc = make_uint4(0u, 0u, 0u, 0u);
    const float4 z = make_float4(0.f, 0.f, 0.f, 0.f);

    for (int ch = 0; ch < CGRP; ch += CSUB) {            // 2 chunks
        const float* sp = src + ((size_t)n * CC + cb + ch) * PLANE;

        // ---- load 26x128 region x 8 channels -> fp16 cells (zero-pad rows) ----
        for (int idx = t; idx < RROWS * WW; idx += NTH) {    // exactly 4 iters
            const int r  = idx >> 7;
            const int J  = idx & 127;
            const int gr = tr0 - HALO5 + r;
            uint4 v = zc;
            if (gr >= 0 && gr < HH) {
                const int o = gr * WW + J;
                v.x = pack2(sp[o],             sp[PLANE + o]);
                v.y = pack2(sp[2 * PLANE + o], sp[3 * PLANE + o]);
                v.z = pack2(sp[4 * PLANE + o], sp[5 * PLANE + o]);
                v.w = pack2(sp[6 * PLANE + o], sp[7 * PLANE + o]);
            }
            bufA[r * RSTR4 + PERM4(J)] = v;
        }
        __syncthreads();

        // ---- 5 fused steps, valid rows shrink top/bottom by 1 per step ----
        uint4* pin  = bufA;
        uint4* pout = bufB;
        for (int st = 0; st < NSTEP; ++st) {
            const int lo = st + 1;
            const int hi = 24 - st;
            if (row >= lo && row <= hi) {
                int wb = (row - 1) * (TAPS * 32) + s;    // half4-cell index
                asm volatile("" : "+v"(wb));             // keep weight reads in-loop
                float4 aL0 = z, aL1 = z, aL2 = z, aL3 = z;
                float4 aH0 = z, aH1 = z, aH2 = z, aH3 = z;
#pragma unroll
                for (int di = 0; di < 3; ++di) {
                    const uint4* rp = pin + (row - 1 + di) * RSTR4;
                    uint4 x[6];
                    x[0] = (s > 0) ? rp[96 + s - 1] : zc;   // col 4s-1
                    x[1] = rp[s];                           // col 4s
                    x[2] = rp[32 + s];                      // col 4s+1
                    x[3] = rp[64 + s];                      // col 4s+2
                    x[4] = rp[96 + s];                      // col 4s+3
                    x[5] = (s < 31) ? rp[s + 1] : zc;       // col 4s+4
#pragma unroll
                    for (int dj = 0; dj < 3; ++dj) {
                        const int k = di * 3 + dj;
                        const uint2 wv = wlds[wb + k * 32];        // ds_read_b64
                        const float2 w01 = __half22float2(*reinterpret_cast<const __half2*>(&wv.x));
                        const float2 w23 = __half22float2(*reinterpret_cast<const __half2*>(&wv.y));
                        aL0 = fma4(cvt_lo(x[0 + dj]), w01.x, aL0);
                        aH0 = fma4(cvt_hi(x[0 + dj]), w01.x, aH0);
                        aL1 = fma4(cvt_lo(x[1 + dj]), w01.y, aL1);
                        aH1 = fma4(cvt_hi(x[1 + dj]), w01.y, aH1);
                        aL2 = fma4(cvt_lo(x[2 + dj]), w23.x, aL2);
                        aH2 = fma4(cvt_hi(x[2 + dj]), w23.x, aH2);
                        aL3 = fma4(cvt_lo(x[3 + dj]), w23.y, aL3);
                        aH3 = fma4(cvt_hi(x[3 + dj]), w23.y, aH3);
                    }
                }
                uint4* op = pout + row * RSTR4;
                uint4 o0, o1, o2, o3;
                o0.x = pack2(aL0.x, aL0.y); o0.y = pack2(aL0.z, aL0.w);
                o0.z = pack2(aH0.x, aH0.y); o0.w = pack2(aH0.z, aH0.w);
                o1.x = pack2(aL1.x, aL1.y); o1.y = pack2(aL1.z, aL1.w);
                o1.z = pack2(aH1.x, aH1.y); o1.w = pack2(aH1.z, aH1.w);
                o2.x = pack2(aL2.x, aL2.y); o2.y = pack2(aL2.z, aL2.w);
                o2.z = pack2(aH2.x, aH2.y); o2.w = pack2(aH2.z, aH2.w);
                o3.x = pack2(aL3.x, aL3.y); o3.y = pack2(aL3.z, aL3.w);
                o3.z = pack2(aH3.x, aH3.y); o3.w = pack2(aH3.z, aH3.w);
                op[s]      = o0;
                op[32 + s] = o1;
                op[64 + s] = o2;
                op[96 + s] = o3;
            }
            __syncthreads();
            uint4* tmp = pin; pin = pout; pout = tmp;
        }

        // ---- store 16x128 core x 8 channels ----
        float* dp = dst + ((size_t)n * CC + cb + ch) * PLANE;
        for (int idx = t; idx < CORE * WW; idx += NTH) {
            const int r = idx >> 7;
            const int J = idx & 127;
            const uint4 v = pin[(r + HALO5) * RSTR4 + PERM4(J)];
            const float4 lo = cvt_lo(v);
            const float4 hi = cvt_hi(v);
            const int o = (tr0 + r) * WW + J;
            dp[o]             = lo.x;
            dp[PLANE + o]     = lo.y;
            dp[2 * PLANE + o] = lo.z;
            dp[3 * PLANE + o] = lo.w;
            dp[4 * PLANE + o] = hi.x;
            dp[5 * PLANE + o] = hi.y;
            dp[6 * PLANE + o] = hi.z;
            dp[7 * PLANE + o] = hi.w;
        }
        __syncthreads();   // protect bufA/wlds before next chunk's load
    }
}

extern "C" void kernel_launch(void* const* d_in, const int* in_sizes, int n_in,
                              void* d_out, int out_size, void* d_ws, size_t ws_size,
                              hipStream_t stream) {
    const float* input  = (const float*)d_in[0];
    const float* weight = (const float*)d_in[1];
    float* out = (float*)d_out;

    uint2* nwh = (uint2*)d_ws;                               // 2.36 MB fp16 weights
    float* B0  = (float*)((char*)d_ws + (size_t)NB * TAPS * PLANE * 2);  // 33.5 MB

    mp_norm_kernel<<<128, 256, 0, stream>>>(weight, nwh);
    mp_fused5_kernel<<<256, NTH, 0, stream>>>(input, B0, nwh);  // steps 1..5
    mp_fused5_kernel<<<256, NTH, 0, stream>>>(B0, out, nwh);    // steps 6..10
}